// Round 6
// baseline (318.135 us; speedup 1.0000x reference)
//
#include <hip/hip_runtime.h>

// ---------------------------------------------------------------------------
// network_49581102465567: 5-layer linear MLP, codebook quantize after layer 2.
// Folds: Wa = w2@w1 [512x1024], Wc = (w5@w4)@w3 [512x512].
// Round 6: (a) bank-conflict-free swizzled LDS placement, DMA-compatible:
//   place(m,g) = m*4 + (((g+(m>>2))^(m&3))&3)  -> 8-way -> 2-way (free).
//   DMA side permutes per-lane global granule within each row's 64B line.
// (b) MODE_Q back to bf16 DMA staging + separate x-cast (R5 fp32 fusion
//   regressed 44->67us). (c) 6 dispatches total. Numerics bit-identical.
// ---------------------------------------------------------------------------

typedef __bf16 v8bf __attribute__((ext_vector_type(8)));
typedef float  v4f  __attribute__((ext_vector_type(4)));

#define Bdim   16384
#define DIN    1024
#define DOUT   512
#define H1dim  4096
#define H3dim  2048
#define H4dim  2048

#define GLOBAL_AS __attribute__((address_space(1)))
#define LDS_AS    __attribute__((address_space(3)))

__device__ __forceinline__ void load16_to_lds(const __bf16* g, __bf16* l) {
  __builtin_amdgcn_global_load_lds((const GLOBAL_AS unsigned int*)g,
                                   (LDS_AS unsigned int*)l, 16, 0, 0);
}

__device__ __forceinline__ unsigned pack2bf(float a, float b) {
  return (unsigned)__builtin_bit_cast(unsigned short, (__bf16)a) |
         ((unsigned)__builtin_bit_cast(unsigned short, (__bf16)b) << 16);
}

// swizzled element offset of 16B granule (row m, 8-elem group g) in [rows][32] bf16 tile
__device__ __forceinline__ int swz(int m, int g) {
  return m * 32 + ((((g + (m >> 2)) ^ (m & 3)) & 3) << 3);
}

// ---- dispatch 1: x cast (blocks 0..16383) + 3 weight transposes ----
__global__ __launch_bounds__(256)
void prep_kernel(const float* __restrict__ x, __bf16* __restrict__ x_bf,
                 const float* __restrict__ w1, __bf16* __restrict__ w1T,
                 const float* __restrict__ w4, __bf16* __restrict__ w4T,
                 const float* __restrict__ w3, __bf16* __restrict__ w3T) {
  const int b = blockIdx.x, t = threadIdx.x;
  if (b < 16384) {
    const int i = b * 256 + t;
    float4 v = reinterpret_cast<const float4*>(x)[i];
    uint2 o;
    o.x = pack2bf(v.x, v.y);
    o.y = pack2bf(v.z, v.w);
    reinterpret_cast<uint2*>(x_bf)[i] = o;
    return;
  }
  __shared__ float tile[32][33];
  const float* in;
  __bf16* outp;
  int R, C, bx, by;
  if (b < 16384 + 4096) {
    const int bb = b - 16384;
    in = w1; outp = w1T; R = H1dim; C = DIN; bx = bb & 31; by = bb >> 5;
  } else if (b < 16384 + 8192) {
    const int bb = b - 20480;
    in = w4; outp = w4T; R = H4dim; C = H3dim; bx = bb & 63; by = bb >> 6;
  } else {
    const int bb = b - 24576;
    in = w3; outp = w3T; R = H3dim; C = DOUT; bx = bb & 15; by = bb >> 4;
  }
  const int c0 = bx * 32, r0 = by * 32;
  const int tr = t >> 5, tc = t & 31;
#pragma unroll
  for (int i = 0; i < 4; ++i)
    tile[tr + i * 8][tc] = in[(size_t)(r0 + tr + i * 8) * C + (c0 + tc)];
  __syncthreads();
#pragma unroll
  for (int i = 0; i < 4; ++i)
    outp[(size_t)(c0 + tr + i * 8) * R + (r0 + tc)] = (__bf16)tile[tc][tr + i * 8];
}

// ---- split-K fold GEMM body: 64x64 tile, swizzled LDS ----
template <bool ABF16>
__device__ __forceinline__ void fold_body(const void* __restrict__ Ain,
                                          const __bf16* __restrict__ Bt,
                                          float* __restrict__ Cpart,
                                          int M, int N, int K, int Kchunk,
                                          int bx, int by, int bz,
                                          __bf16* As, __bf16* Bs) {
  const int t = threadIdx.x;
  const int m0 = bx * 64, n0 = by * 64, kbeg = bz * Kchunk;
  const int lane = t & 63, wave = t >> 6;
  const int quad = lane >> 4, l15 = lane & 15;
  const int wm = (wave & 1) * 32, wn = (wave >> 1) * 32;

  v4f acc[2][2];
#pragma unroll
  for (int i = 0; i < 2; ++i)
#pragma unroll
    for (int j = 0; j < 2; ++j) acc[i][j] = (v4f){0.f, 0.f, 0.f, 0.f};

  const int r = t >> 2, cg = t & 3;
  for (int k0 = kbeg; k0 < kbeg + Kchunk; k0 += 32) {
    if constexpr (ABF16) {
      const __bf16* A = (const __bf16*)Ain;
      *(int4*)&As[swz(r, cg)] = *(const int4*)&A[(size_t)(m0 + r) * K + k0 + cg * 8];
    } else {
      const float* A = (const float*)Ain;
#pragma unroll
      for (int p2 = 0; p2 < 2; ++p2) {
        const int idx = p2 * 256 + t;
        const int row = idx >> 3, half = idx & 1, gg = (idx & 7) >> 1;
        float4 v = *(const float4*)&A[(size_t)(m0 + row) * K + k0 + (idx & 7) * 4];
        uint2 o;
        o.x = pack2bf(v.x, v.y);
        o.y = pack2bf(v.z, v.w);
        *(uint2*)&As[swz(row, gg) + half * 4] = o;
      }
    }
    *(int4*)&Bs[swz(r, cg)] = *(const int4*)&Bt[(size_t)(n0 + r) * K + k0 + cg * 8];
    __syncthreads();
    v8bf af[2], bfr[2];
#pragma unroll
    for (int i = 0; i < 2; ++i) {
      af[i]  = *(const v8bf*)&As[swz(wm + i * 16 + l15, quad)];
      bfr[i] = *(const v8bf*)&Bs[swz(wn + i * 16 + l15, quad)];
    }
#pragma unroll
    for (int i = 0; i < 2; ++i)
#pragma unroll
      for (int j = 0; j < 2; ++j)
        acc[i][j] = __builtin_amdgcn_mfma_f32_16x16x32_bf16(af[i], bfr[j], acc[i][j], 0, 0, 0);
    __syncthreads();
  }

  float* dst = Cpart + (size_t)bz * M * N;
#pragma unroll
  for (int i = 0; i < 2; ++i)
#pragma unroll
    for (int j = 0; j < 2; ++j)
#pragma unroll
      for (int r2 = 0; r2 < 4; ++r2) {
        const int gm = m0 + wm + i * 16 + quad * 4 + r2;
        const int gn = n0 + wn + j * 16 + l15;
        dst[(size_t)gm * N + gn] = acc[i][j][r2];
      }
}

// ---- dispatch 2: fold1 (blocks 0..1023) + fold2 (1024..2047) ----
__global__ __launch_bounds__(256, 4)
void fold12_kernel(const float* __restrict__ w2, const __bf16* __restrict__ w1T,
                   float* __restrict__ part1,
                   const float* __restrict__ w5, const __bf16* __restrict__ w4T,
                   float* __restrict__ part2) {
  __shared__ __bf16 As[64 * 32];
  __shared__ __bf16 Bs[64 * 32];
  int b = blockIdx.x;
  if (b < 1024) {
    fold_body<false>(w2, w1T, part1, DOUT, DIN, H1dim, 512,
                     b & 7, (b >> 3) & 15, b >> 7, As, Bs);
  } else {
    b -= 1024;
    fold_body<false>(w5, w4T, part2, DOUT, H3dim, H4dim, 512,
                     b & 7, (b >> 3) & 31, b >> 8, As, Bs);
  }
}

__device__ __forceinline__ void reduce_body(const float* __restrict__ part,
                                            __bf16* __restrict__ out,
                                            int i, int MN4, int S) {
  const float4* p = reinterpret_cast<const float4*>(part);
  float4 s = p[i];
  for (int k = 1; k < S; ++k) {
    float4 v = p[(size_t)k * MN4 + i];
    s.x += v.x; s.y += v.y; s.z += v.z; s.w += v.w;
  }
  uint2 o;
  o.x = pack2bf(s.x, s.y);
  o.y = pack2bf(s.z, s.w);
  reinterpret_cast<uint2*>(out)[i] = o;
}

// ---- dispatch 3: reduce1 (0..511) + reduce2 (512..1535) ----
__global__ __launch_bounds__(256)
void reduce12_kernel(const float* __restrict__ part1, __bf16* __restrict__ WaT,
                     const float* __restrict__ part2, __bf16* __restrict__ WtT) {
  const int b = blockIdx.x, t = threadIdx.x;
  if (b < 512) reduce_body(part1, WaT, b * 256 + t, 131072, 8);
  else         reduce_body(part2, WtT, (b - 512) * 256 + t, 262144, 4);
}

// ---- dispatch 4: fold3 (0..511) + bias ba/bc (512..767) ----
__global__ __launch_bounds__(256, 4)
void fold3bias_kernel(const __bf16* __restrict__ WtT, const __bf16* __restrict__ w3T,
                      float* __restrict__ part1,
                      const float* __restrict__ b1, const float* __restrict__ w2,
                      const float* __restrict__ b2, const float* __restrict__ b3,
                      const float* __restrict__ b4, const float* __restrict__ w5,
                      const float* __restrict__ b5,
                      float* __restrict__ ba, float* __restrict__ bc) {
  __shared__ __bf16 As[64 * 32];
  __shared__ __bf16 Bs[64 * 32];
  int b = blockIdx.x;
  if (b < 512) {
    fold_body<true>(WtT, w3T, part1, DOUT, DOUT, H3dim, 256,
                    b & 7, (b >> 3) & 7, b >> 6, As, Bs);
    return;
  }
  b -= 512;
  const int wave = threadIdx.x >> 6, lane = threadIdx.x & 63;
  if (b < 128) {
    const int j = b * 4 + wave;
    float s = 0.f;
    for (int k = lane; k < H1dim; k += 64) s += b1[k] * w2[(size_t)j * H1dim + k];
#pragma unroll
    for (int off = 32; off; off >>= 1) s += __shfl_xor(s, off, 64);
    if (lane == 0) ba[j] = s + b2[j];
  } else {
    const int j = (b - 128) * 4 + wave;
    float s = 0.f;
    for (int k = lane; k < H4dim; k += 64)
      s += b3[k] * (float)WtT[(size_t)j * H4dim + k] + b4[k] * w5[(size_t)j * H4dim + k];
#pragma unroll
    for (int off = 32; off; off >>= 1) s += __shfl_xor(s, off, 64);
    if (lane == 0) bc[j] = s + b5[j];
  }
}

// ---- main B^T GEMM body: 128x64 tile, DMA staging, swizzled LDS ----
enum { MODE_Q = 1, MODE_OUT = 2 };

template <int MODE>
__device__ __forceinline__ void gemm_main(const __bf16* __restrict__ A,
                                          const __bf16* __restrict__ Bt,
                                          void* __restrict__ Cout,
                                          const float* __restrict__ bias,
                                          const float* __restrict__ codebook,
                                          int K, int N, int mb, int nb,
                                          __bf16* As, __bf16* Bs, float* cbs) {
  const int t = threadIdx.x;
  const int m0 = mb * 128, n0 = nb * 64;
  if constexpr (MODE == MODE_Q) cbs[t] = codebook[t];  // covered by 1st barrier

  const int lane = t & 63, wave = t >> 6;
  const int quad = lane >> 4, l15 = lane & 15;
  const int wm = (wave & 1) * 64, wn = (wave >> 1) * 32;

  // DMA: chunk = 16 rows x 64B; lane l -> row lrow=l/4, permuted granule g
  // so data lands at swizzled place (place-in-row == l%4). Wave-independent.
  const int lrow = lane >> 2;
  const int g = (((lane & 3) ^ (lrow & 3)) - (lrow >> 2)) & 3;
  const int scol = g * 8;
  const __bf16* gA0 = A + (size_t)(m0 + 16 * wave + lrow) * K + scol;
  const __bf16* gA1 = A + (size_t)(m0 + 64 + 16 * wave + lrow) * K + scol;
  const __bf16* gB0 = Bt + (size_t)(n0 + 16 * wave + lrow) * K + scol;
  __bf16* lA0 = &As[wave * 512];
  __bf16* lA1 = &As[(wave + 4) * 512];
  __bf16* lB0 = &Bs[wave * 512];

  v4f acc[4][2];
#pragma unroll
  for (int i = 0; i < 4; ++i)
#pragma unroll
    for (int j = 0; j < 2; ++j) acc[i][j] = (v4f){0.f, 0.f, 0.f, 0.f};

  for (int k0 = 0; k0 < K; k0 += 32) {
    load16_to_lds(gB0 + k0, lB0);
    load16_to_lds(gA0 + k0, lA0);
    load16_to_lds(gA1 + k0, lA1);
    __syncthreads();

    v8bf af[4], bfr[2];
#pragma unroll
    for (int i = 0; i < 4; ++i)
      af[i] = *(const v8bf*)&As[swz(wm + i * 16 + l15, quad)];
#pragma unroll
    for (int j = 0; j < 2; ++j)
      bfr[j] = *(const v8bf*)&Bs[swz(wn + j * 16 + l15, quad)];
#pragma unroll
    for (int i = 0; i < 4; ++i)
#pragma unroll
      for (int j = 0; j < 2; ++j)
        acc[i][j] = __builtin_amdgcn_mfma_f32_16x16x32_bf16(af[i], bfr[j], acc[i][j], 0, 0, 0);
    __syncthreads();
  }

#pragma unroll
  for (int i = 0; i < 4; ++i) {
#pragma unroll
    for (int j = 0; j < 2; ++j) {
#pragma unroll
      for (int r = 0; r < 4; ++r) {
        const int gm = m0 + wm + i * 16 + quad * 4 + r;
        const int gn = n0 + wn + j * 16 + l15;
        float v = acc[i][j][r];
        if constexpr (MODE == MODE_Q) {
          v += bias[gn];
          int idx = 0;
#pragma unroll
          for (int s = 128; s > 0; s >>= 1) {
            const int u = idx + s;
            if (cbs[u] <= v) idx = u;
          }
          float best = cbs[idx];
          if (idx < 255) {
            const float c1 = cbs[idx + 1];
            if (!(v - best <= c1 - v)) best = c1;
          }
          ((__bf16*)Cout)[(size_t)gm * N + gn] = (__bf16)best;
        } else {
          v += bias[gn];
          ((float*)Cout)[(size_t)gm * N + gn] = v;
        }
      }
    }
  }
}

// ---- dispatch 5: MODE_Q gemm (0..1023) + reduce3 -> WcT (1024..1279) ----
__global__ __launch_bounds__(256, 4)
void gemmq_kernel(const __bf16* __restrict__ x_bf, const __bf16* __restrict__ WaT,
                  __bf16* __restrict__ q, const float* __restrict__ ba,
                  const float* __restrict__ cbk,
                  const float* __restrict__ part1, __bf16* __restrict__ WcT) {
  __shared__ __bf16 As[128 * 32];
  __shared__ __bf16 Bs[64 * 32];
  __shared__ float cbs[256];
  const int b = blockIdx.x;
  if (b < 1024) {
    gemm_main<MODE_Q>(x_bf, WaT, q, ba, cbk, DIN, DOUT, b >> 3, b & 7, As, Bs, cbs);
  } else {
    reduce_body(part1, WcT, (b - 1024) * 256 + threadIdx.x, 65536, 8);
  }
}

// ---- dispatch 6: MODE_OUT gemm ----
__global__ __launch_bounds__(256, 4)
void gemmout_kernel(const __bf16* __restrict__ q, const __bf16* __restrict__ WcT,
                    float* __restrict__ out, const float* __restrict__ bc) {
  __shared__ __bf16 As[128 * 32];
  __shared__ __bf16 Bs[64 * 32];
  const int b = blockIdx.x;
  gemm_main<MODE_OUT>(q, WcT, out, bc, nullptr, DOUT, DOUT, b >> 3, b & 7, As, Bs, nullptr);
}

extern "C" void kernel_launch(void* const* d_in, const int* in_sizes, int n_in,
                              void* d_out, int out_size, void* d_ws, size_t ws_size,
                              hipStream_t stream) {
  const float* x  = (const float*)d_in[0];
  const float* cb = (const float*)d_in[1];
  const float* w1 = (const float*)d_in[2];   // [4096,1024]
  const float* b1 = (const float*)d_in[3];
  const float* w2 = (const float*)d_in[4];   // [512,4096]
  const float* b2 = (const float*)d_in[5];
  const float* w3 = (const float*)d_in[6];   // [2048,512]
  const float* b3 = (const float*)d_in[7];
  const float* w4 = (const float*)d_in[8];   // [2048,2048]
  const float* b4 = (const float*)d_in[9];
  const float* w5 = (const float*)d_in[10];  // [512,2048]
  const float* b5 = (const float*)d_in[11];
  float* out = (float*)d_out;

  char* ws = (char*)d_ws;
  size_t off = 0;
  auto alloc = [&](size_t bytes) -> void* {
    void* p = ws + off;
    off = (off + bytes + 255) & ~(size_t)255;
    return p;
  };
  __bf16* x_bf  = (__bf16*)alloc((size_t)Bdim * DIN * 2);     // 33.5 MB
  __bf16* w1T   = (__bf16*)alloc((size_t)DIN * H1dim * 2);    // 8 MB
  __bf16* w4T   = (__bf16*)alloc((size_t)H3dim * H4dim * 2);  // 8 MB
  __bf16* w3T   = (__bf16*)alloc((size_t)DOUT * H3dim * 2);   // 2 MB
  __bf16* WaT   = (__bf16*)alloc((size_t)DOUT * DIN * 2);     // 1 MB
  __bf16* WtT   = (__bf16*)alloc((size_t)DOUT * H3dim * 2);   // 2 MB
  __bf16* WcT   = (__bf16*)alloc((size_t)DOUT * DOUT * 2);    // 0.5 MB
  float*  ba    = (float*)alloc(DOUT * 4);
  float*  bc    = (float*)alloc(DOUT * 4);
  float*  part1 = (float*)alloc((size_t)8 * DOUT * DIN * 4);   // 16.8 MB
  float*  part2 = (float*)alloc((size_t)4 * DOUT * H3dim * 4); // 16.8 MB
  // q aliases part2: part2 is dead after reduce12; q written in dispatch 5.
  __bf16* q     = (__bf16*)part2;                              // 16.8 MB

  // 1. x cast + 3 transposes (16384 + 4096 + 4096 + 1024 = 25600 blocks)
  prep_kernel<<<25600, 256, 0, stream>>>(x, x_bf, w1, w1T, w4, w4T, w3, w3T);
  // 2. fold1 (WaT partials) + fold2 (WtT partials)
  fold12_kernel<<<2048, 256, 0, stream>>>(w2, w1T, part1, w5, w4T, part2);
  // 3. reduce -> WaT, WtT
  reduce12_kernel<<<1536, 256, 0, stream>>>(part1, WaT, part2, WtT);
  // 4. fold3 (WcT partials, reuses part1) + folded biases ba/bc
  fold3bias_kernel<<<768, 256, 0, stream>>>(WtT, w3T, part1,
                                            b1, w2, b2, b3, b4, w5, b5, ba, bc);
  // 5. h2 = x@Wa + ba -> quantize -> q   ; plus reduce3 -> WcT
  gemmq_kernel<<<1280, 256, 0, stream>>>(x_bf, WaT, q, ba, cb, part1, WcT);
  // 6. out = q@Wc + bc
  gemmout_kernel<<<1024, 256, 0, stream>>>(q, WcT, out, bc);
}

// Round 7
// 316.559 us; speedup vs baseline: 1.0050x; 1.0050x over previous
//
#include <hip/hip_runtime.h>

// ---------------------------------------------------------------------------
// network_49581102465567: 5-layer linear MLP, codebook quantize after layer 2.
// Folds: Wa = w2@w1 [512x1024], Wc = (w5@w4)@w3 [512x512].
// Round 7: (a) REVERT R6 swizzle/granule-permutation (broke DMA coalescing:
// FETCH 20.6->136MB, 4x over-fetch; conflict counter proved inert).
// (b) Double-buffered LDS in main GEMMs: DMA(k+1) issued post-barrier,
// overlaps reads+MFMA of tile k, drained at next barrier. One barrier/iter.
// Numerics bit-identical to R4/R5.
// ---------------------------------------------------------------------------

typedef __bf16 v8bf __attribute__((ext_vector_type(8)));
typedef float  v4f  __attribute__((ext_vector_type(4)));

#define Bdim   16384
#define DIN    1024
#define DOUT   512
#define H1dim  4096
#define H3dim  2048
#define H4dim  2048

#define GLOBAL_AS __attribute__((address_space(1)))
#define LDS_AS    __attribute__((address_space(3)))

__device__ __forceinline__ void load16_to_lds(const __bf16* g, __bf16* l) {
  __builtin_amdgcn_global_load_lds((const GLOBAL_AS unsigned int*)g,
                                   (LDS_AS unsigned int*)l, 16, 0, 0);
}

__device__ __forceinline__ unsigned pack2bf(float a, float b) {
  return (unsigned)__builtin_bit_cast(unsigned short, (__bf16)a) |
         ((unsigned)__builtin_bit_cast(unsigned short, (__bf16)b) << 16);
}

// ---- dispatch 1: x cast (blocks 0..16383) + 3 weight transposes ----
__global__ __launch_bounds__(256)
void prep_kernel(const float* __restrict__ x, __bf16* __restrict__ x_bf,
                 const float* __restrict__ w1, __bf16* __restrict__ w1T,
                 const float* __restrict__ w4, __bf16* __restrict__ w4T,
                 const float* __restrict__ w3, __bf16* __restrict__ w3T) {
  const int b = blockIdx.x, t = threadIdx.x;
  if (b < 16384) {
    const int i = b * 256 + t;
    float4 v = reinterpret_cast<const float4*>(x)[i];
    uint2 o;
    o.x = pack2bf(v.x, v.y);
    o.y = pack2bf(v.z, v.w);
    reinterpret_cast<uint2*>(x_bf)[i] = o;
    return;
  }
  __shared__ float tile[32][33];
  const float* in;
  __bf16* outp;
  int R, C, bx, by;
  if (b < 16384 + 4096) {
    const int bb = b - 16384;
    in = w1; outp = w1T; R = H1dim; C = DIN; bx = bb & 31; by = bb >> 5;
  } else if (b < 16384 + 8192) {
    const int bb = b - 20480;
    in = w4; outp = w4T; R = H4dim; C = H3dim; bx = bb & 63; by = bb >> 6;
  } else {
    const int bb = b - 24576;
    in = w3; outp = w3T; R = H3dim; C = DOUT; bx = bb & 15; by = bb >> 4;
  }
  const int c0 = bx * 32, r0 = by * 32;
  const int tr = t >> 5, tc = t & 31;
#pragma unroll
  for (int i = 0; i < 4; ++i)
    tile[tr + i * 8][tc] = in[(size_t)(r0 + tr + i * 8) * C + (c0 + tc)];
  __syncthreads();
#pragma unroll
  for (int i = 0; i < 4; ++i)
    outp[(size_t)(c0 + tr + i * 8) * R + (r0 + tc)] = (__bf16)tile[tc][tr + i * 8];
}

// ---- split-K fold GEMM body: 64x64 tile, linear LDS ----
template <bool ABF16>
__device__ __forceinline__ void fold_body(const void* __restrict__ Ain,
                                          const __bf16* __restrict__ Bt,
                                          float* __restrict__ Cpart,
                                          int M, int N, int K, int Kchunk,
                                          int bx, int by, int bz,
                                          __bf16* As, __bf16* Bs) {
  const int t = threadIdx.x;
  const int m0 = bx * 64, n0 = by * 64, kbeg = bz * Kchunk;
  const int lane = t & 63, wave = t >> 6;
  const int quad = lane >> 4, l15 = lane & 15;
  const int wm = (wave & 1) * 32, wn = (wave >> 1) * 32;

  v4f acc[2][2];
#pragma unroll
  for (int i = 0; i < 2; ++i)
#pragma unroll
    for (int j = 0; j < 2; ++j) acc[i][j] = (v4f){0.f, 0.f, 0.f, 0.f};

  const int e = t * 8, r = e >> 5, c = e & 31;
  for (int k0 = kbeg; k0 < kbeg + Kchunk; k0 += 32) {
    if constexpr (ABF16) {
      const __bf16* A = (const __bf16*)Ain;
      *(int4*)&As[e] = *(const int4*)&A[(size_t)(m0 + r) * K + (k0 + c)];
    } else {
      const float* A = (const float*)Ain;
#pragma unroll
      for (int p2 = 0; p2 < 2; ++p2) {
        const int idx = p2 * 256 + t;
        const int row = idx >> 3, col = (idx & 7) * 4;
        float4 v = *(const float4*)&A[(size_t)(m0 + row) * K + (k0 + col)];
        uint2 o;
        o.x = pack2bf(v.x, v.y);
        o.y = pack2bf(v.z, v.w);
        *(uint2*)&As[row * 32 + col] = o;
      }
    }
    *(int4*)&Bs[e] = *(const int4*)&Bt[(size_t)(n0 + r) * K + (k0 + c)];
    __syncthreads();
    v8bf af[2], bfr[2];
#pragma unroll
    for (int i = 0; i < 2; ++i) {
      af[i]  = *(const v8bf*)&As[(wm + i * 16 + l15) * 32 + quad * 8];
      bfr[i] = *(const v8bf*)&Bs[(wn + i * 16 + l15) * 32 + quad * 8];
    }
#pragma unroll
    for (int i = 0; i < 2; ++i)
#pragma unroll
      for (int j = 0; j < 2; ++j)
        acc[i][j] = __builtin_amdgcn_mfma_f32_16x16x32_bf16(af[i], bfr[j], acc[i][j], 0, 0, 0);
    __syncthreads();
  }

  float* dst = Cpart + (size_t)bz * M * N;
#pragma unroll
  for (int i = 0; i < 2; ++i)
#pragma unroll
    for (int j = 0; j < 2; ++j)
#pragma unroll
      for (int r2 = 0; r2 < 4; ++r2) {
        const int gm = m0 + wm + i * 16 + quad * 4 + r2;
        const int gn = n0 + wn + j * 16 + l15;
        dst[(size_t)gm * N + gn] = acc[i][j][r2];
      }
}

// ---- dispatch 2: fold1 (blocks 0..1023) + fold2 (1024..2047) ----
__global__ __launch_bounds__(256, 4)
void fold12_kernel(const float* __restrict__ w2, const __bf16* __restrict__ w1T,
                   float* __restrict__ part1,
                   const float* __restrict__ w5, const __bf16* __restrict__ w4T,
                   float* __restrict__ part2) {
  __shared__ __bf16 As[64 * 32];
  __shared__ __bf16 Bs[64 * 32];
  int b = blockIdx.x;
  if (b < 1024) {
    fold_body<false>(w2, w1T, part1, DOUT, DIN, H1dim, 512,
                     b & 7, (b >> 3) & 15, b >> 7, As, Bs);
  } else {
    b -= 1024;
    fold_body<false>(w5, w4T, part2, DOUT, H3dim, H4dim, 512,
                     b & 7, (b >> 3) & 31, b >> 8, As, Bs);
  }
}

__device__ __forceinline__ void reduce_body(const float* __restrict__ part,
                                            __bf16* __restrict__ out,
                                            int i, int MN4, int S) {
  const float4* p = reinterpret_cast<const float4*>(part);
  float4 s = p[i];
  for (int k = 1; k < S; ++k) {
    float4 v = p[(size_t)k * MN4 + i];
    s.x += v.x; s.y += v.y; s.z += v.z; s.w += v.w;
  }
  uint2 o;
  o.x = pack2bf(s.x, s.y);
  o.y = pack2bf(s.z, s.w);
  reinterpret_cast<uint2*>(out)[i] = o;
}

// ---- dispatch 3: reduce1 (0..511) + reduce2 (512..1535) ----
__global__ __launch_bounds__(256)
void reduce12_kernel(const float* __restrict__ part1, __bf16* __restrict__ WaT,
                     const float* __restrict__ part2, __bf16* __restrict__ WtT) {
  const int b = blockIdx.x, t = threadIdx.x;
  if (b < 512) reduce_body(part1, WaT, b * 256 + t, 131072, 8);
  else         reduce_body(part2, WtT, (b - 512) * 256 + t, 262144, 4);
}

// ---- dispatch 4: fold3 (0..511) + bias ba/bc (512..767) ----
__global__ __launch_bounds__(256, 4)
void fold3bias_kernel(const __bf16* __restrict__ WtT, const __bf16* __restrict__ w3T,
                      float* __restrict__ part1,
                      const float* __restrict__ b1, const float* __restrict__ w2,
                      const float* __restrict__ b2, const float* __restrict__ b3,
                      const float* __restrict__ b4, const float* __restrict__ w5,
                      const float* __restrict__ b5,
                      float* __restrict__ ba, float* __restrict__ bc) {
  __shared__ __bf16 As[64 * 32];
  __shared__ __bf16 Bs[64 * 32];
  int b = blockIdx.x;
  if (b < 512) {
    fold_body<true>(WtT, w3T, part1, DOUT, DOUT, H3dim, 256,
                    b & 7, (b >> 3) & 7, b >> 6, As, Bs);
    return;
  }
  b -= 512;
  const int wave = threadIdx.x >> 6, lane = threadIdx.x & 63;
  if (b < 128) {
    const int j = b * 4 + wave;
    float s = 0.f;
    for (int k = lane; k < H1dim; k += 64) s += b1[k] * w2[(size_t)j * H1dim + k];
#pragma unroll
    for (int off = 32; off; off >>= 1) s += __shfl_xor(s, off, 64);
    if (lane == 0) ba[j] = s + b2[j];
  } else {
    const int j = (b - 128) * 4 + wave;
    float s = 0.f;
    for (int k = lane; k < H4dim; k += 64)
      s += b3[k] * (float)WtT[(size_t)j * H4dim + k] + b4[k] * w5[(size_t)j * H4dim + k];
#pragma unroll
    for (int off = 32; off; off >>= 1) s += __shfl_xor(s, off, 64);
    if (lane == 0) bc[j] = s + b5[j];
  }
}

// ---- main B^T GEMM body: 128x64 tile, DMA staging, DOUBLE-BUFFERED LDS ----
// Loop shape: barrier; DMA(next tile -> alt buf); ds_read(cur); MFMA.
// DMA flies during reads+MFMA, drained by NEXT iteration's barrier.
enum { MODE_Q = 1, MODE_OUT = 2 };

template <int MODE>
__device__ __forceinline__ void gemm_main(const __bf16* __restrict__ A,
                                          const __bf16* __restrict__ Bt,
                                          void* __restrict__ Cout,
                                          const float* __restrict__ bias,
                                          const float* __restrict__ codebook,
                                          int K, int N, int mb, int nb,
                                          __bf16* As, __bf16* Bs, float* cbs) {
  const int t = threadIdx.x;
  const int m0 = mb * 128, n0 = nb * 64;
  if constexpr (MODE == MODE_Q) cbs[t] = codebook[t];  // covered by 1st barrier

  const int lane = t & 63, wave = t >> 6;
  const int quad = lane >> 4, l15 = lane & 15;
  const int wm = (wave & 1) * 64, wn = (wave >> 1) * 32;

  // staging (linear, DMA-coalesced): chunk = 16 rows x 64B; wave w -> A chunks
  // {w, w+4}, B chunk {w}; lane l -> row l>>2, 16B granule l&3.
  const int lrow = lane >> 2;
  const int scol = (lane & 3) * 8;
  const __bf16* gA0 = A + (size_t)(m0 + 16 * wave + lrow) * K + scol;
  const __bf16* gA1 = A + (size_t)(m0 + 64 + 16 * wave + lrow) * K + scol;
  const __bf16* gB0 = Bt + (size_t)(n0 + 16 * wave + lrow) * K + scol;

  v4f acc[4][2];
#pragma unroll
  for (int i = 0; i < 4; ++i)
#pragma unroll
    for (int j = 0; j < 2; ++j) acc[i][j] = (v4f){0.f, 0.f, 0.f, 0.f};

  // preload tile 0 into buffer 0
  load16_to_lds(gB0, &Bs[wave * 512]);
  load16_to_lds(gA0, &As[wave * 512]);
  load16_to_lds(gA1, &As[(wave + 4) * 512]);

  const int NIT = K >> 5;
  for (int it = 0; it < NIT; ++it) {
    __syncthreads();  // drains DMA for buf[it&1]; also closes prev iter's reads
    const int cur = it & 1;
    __bf16* Ac = &As[cur * 4096];
    __bf16* Bc = &Bs[cur * 2048];
    if (it + 1 < NIT) {
      const int nxt = cur ^ 1;
      const int k0 = (it + 1) << 5;
      load16_to_lds(gB0 + k0, &Bs[nxt * 2048 + wave * 512]);
      load16_to_lds(gA0 + k0, &As[nxt * 4096 + wave * 512]);
      load16_to_lds(gA1 + k0, &As[nxt * 4096 + (wave + 4) * 512]);
    }

    v8bf af[4], bfr[2];
#pragma unroll
    for (int i = 0; i < 4; ++i)
      af[i] = *(const v8bf*)&Ac[(wm + i * 16 + l15) * 32 + quad * 8];
#pragma unroll
    for (int j = 0; j < 2; ++j)
      bfr[j] = *(const v8bf*)&Bc[(wn + j * 16 + l15) * 32 + quad * 8];
#pragma unroll
    for (int i = 0; i < 4; ++i)
#pragma unroll
      for (int j = 0; j < 2; ++j)
        acc[i][j] = __builtin_amdgcn_mfma_f32_16x16x32_bf16(af[i], bfr[j], acc[i][j], 0, 0, 0);
  }

#pragma unroll
  for (int i = 0; i < 4; ++i) {
#pragma unroll
    for (int j = 0; j < 2; ++j) {
#pragma unroll
      for (int r = 0; r < 4; ++r) {
        const int gm = m0 + wm + i * 16 + quad * 4 + r;
        const int gn = n0 + wn + j * 16 + l15;
        float v = acc[i][j][r];
        if constexpr (MODE == MODE_Q) {
          v += bias[gn];
          int idx = 0;
#pragma unroll
          for (int s = 128; s > 0; s >>= 1) {
            const int u = idx + s;
            if (cbs[u] <= v) idx = u;
          }
          float best = cbs[idx];
          if (idx < 255) {
            const float c1 = cbs[idx + 1];
            if (!(v - best <= c1 - v)) best = c1;
          }
          ((__bf16*)Cout)[(size_t)gm * N + gn] = (__bf16)best;
        } else {
          v += bias[gn];
          ((float*)Cout)[(size_t)gm * N + gn] = v;
        }
      }
    }
  }
}

// ---- dispatch 5: MODE_Q gemm (0..1023) + reduce3 -> WcT (1024..1279) ----
__global__ __launch_bounds__(256, 4)
void gemmq_kernel(const __bf16* __restrict__ x_bf, const __bf16* __restrict__ WaT,
                  __bf16* __restrict__ q, const float* __restrict__ ba,
                  const float* __restrict__ cbk,
                  const float* __restrict__ part1, __bf16* __restrict__ WcT) {
  __shared__ __bf16 As[2 * 128 * 32];  // 16 KB double-buffered
  __shared__ __bf16 Bs[2 * 64 * 32];   //  8 KB double-buffered
  __shared__ float cbs[256];
  const int b = blockIdx.x;
  if (b < 1024) {
    gemm_main<MODE_Q>(x_bf, WaT, q, ba, cbk, DIN, DOUT, b >> 3, b & 7, As, Bs, cbs);
  } else {
    reduce_body(part1, WcT, (b - 1024) * 256 + threadIdx.x, 65536, 8);
  }
}

// ---- dispatch 6: MODE_OUT gemm ----
__global__ __launch_bounds__(256, 4)
void gemmout_kernel(const __bf16* __restrict__ q, const __bf16* __restrict__ WcT,
                    float* __restrict__ out, const float* __restrict__ bc) {
  __shared__ __bf16 As[2 * 128 * 32];
  __shared__ __bf16 Bs[2 * 64 * 32];
  const int b = blockIdx.x;
  gemm_main<MODE_OUT>(q, WcT, out, bc, nullptr, DOUT, DOUT, b >> 3, b & 7, As, Bs, nullptr);
}

extern "C" void kernel_launch(void* const* d_in, const int* in_sizes, int n_in,
                              void* d_out, int out_size, void* d_ws, size_t ws_size,
                              hipStream_t stream) {
  const float* x  = (const float*)d_in[0];
  const float* cb = (const float*)d_in[1];
  const float* w1 = (const float*)d_in[2];   // [4096,1024]
  const float* b1 = (const float*)d_in[3];
  const float* w2 = (const float*)d_in[4];   // [512,4096]
  const float* b2 = (const float*)d_in[5];
  const float* w3 = (const float*)d_in[6];   // [2048,512]
  const float* b3 = (const float*)d_in[7];
  const float* w4 = (const float*)d_in[8];   // [2048,2048]
  const float* b4 = (const float*)d_in[9];
  const float* w5 = (const float*)d_in[10];  // [512,2048]
  const float* b5 = (const float*)d_in[11];
  float* out = (float*)d_out;

  char* ws = (char*)d_ws;
  size_t off = 0;
  auto alloc = [&](size_t bytes) -> void* {
    void* p = ws + off;
    off = (off + bytes + 255) & ~(size_t)255;
    return p;
  };
  __bf16* x_bf  = (__bf16*)alloc((size_t)Bdim * DIN * 2);     // 33.5 MB
  __bf16* w1T   = (__bf16*)alloc((size_t)DIN * H1dim * 2);    // 8 MB
  __bf16* w4T   = (__bf16*)alloc((size_t)H3dim * H4dim * 2);  // 8 MB
  __bf16* w3T   = (__bf16*)alloc((size_t)DOUT * H3dim * 2);   // 2 MB
  __bf16* WaT   = (__bf16*)alloc((size_t)DOUT * DIN * 2);     // 1 MB
  __bf16* WtT   = (__bf16*)alloc((size_t)DOUT * H3dim * 2);   // 2 MB
  __bf16* WcT   = (__bf16*)alloc((size_t)DOUT * DOUT * 2);    // 0.5 MB
  float*  ba    = (float*)alloc(DOUT * 4);
  float*  bc    = (float*)alloc(DOUT * 4);
  float*  part1 = (float*)alloc((size_t)8 * DOUT * DIN * 4);   // 16.8 MB
  float*  part2 = (float*)alloc((size_t)4 * DOUT * H3dim * 4); // 16.8 MB
  // q aliases part2: part2 is dead after reduce12; q written in dispatch 5.
  __bf16* q     = (__bf16*)part2;                              // 16.8 MB

  // 1. x cast + 3 transposes
  prep_kernel<<<25600, 256, 0, stream>>>(x, x_bf, w1, w1T, w4, w4T, w3, w3T);
  // 2. fold1 (WaT partials) + fold2 (WtT partials)
  fold12_kernel<<<2048, 256, 0, stream>>>(w2, w1T, part1, w5, w4T, part2);
  // 3. reduce -> WaT, WtT
  reduce12_kernel<<<1536, 256, 0, stream>>>(part1, WaT, part2, WtT);
  // 4. fold3 (WcT partials, reuses part1) + folded biases ba/bc
  fold3bias_kernel<<<768, 256, 0, stream>>>(WtT, w3T, part1,
                                            b1, w2, b2, b3, b4, w5, b5, ba, bc);
  // 5. h2 = x@Wa + ba -> quantize -> q ; plus reduce3 -> WcT
  gemmq_kernel<<<1280, 256, 0, stream>>>(x_bf, WaT, q, ba, cb, part1, WcT);
  // 6. out = q@Wc + bc
  gemmout_kernel<<<1024, 256, 0, stream>>>(q, WcT, out, bc);
}